// Round 3
// baseline (450.983 us; speedup 1.0000x reference)
//
#include <hip/hip_runtime.h>
#include <math.h>

#define DC_C 6
#define NRANGE 8          // slot ranges, aligned to blockIdx%8 -> XCD round-robin
#define BCH 2048          // edges per block-chunk in build_b

// Phase A: per edge e, claim slot j in check c via device atomic, write
// pos[e] = c*6+j (coalesced int4). 4 edges/thread -> 4 atomics in flight.
// No v2c init: iteration 0 gathers llr directly (v2c_0[e] == llr[e/3]).
__global__ __launch_bounds__(256) void build_a(const int4* __restrict__ edge_chk4,
                                               int* __restrict__ cnt,
                                               int4* __restrict__ pos4,
                                               int E4) {
    int t = blockIdx.x * blockDim.x + threadIdx.x;
    if (t >= E4) return;
    int4 c = edge_chk4[t];
    int j0 = atomicAdd(&cnt[c.x], 1);
    int j1 = atomicAdd(&cnt[c.y], 1);
    int j2 = atomicAdd(&cnt[c.z], 1);
    int j3 = atomicAdd(&cnt[c.w], 1);
    pos4[t] = make_int4(c.x * DC_C + j0, c.y * DC_C + j1,
                        c.z * DC_C + j2, c.w * DC_C + j3);
}

// Phase B: invert pos -> idx (slot -> edge). Only random write in the
// pipeline; range-partitioned so each idx line is filled from one XCD
// (blockIdx%8 heuristic; perf-only, correctness-independent).
// Each thread reads 8 edges via 2x int4 coalesced loads.
__global__ __launch_bounds__(256) void build_b(const int4* __restrict__ pos4,
                                               int* __restrict__ idx,
                                               int E) {
    int r = blockIdx.x & (NRANGE - 1);
    int chunk = blockIdx.x >> 3;
    int lo = r * (E / NRANGE);
    int hi = lo + (E / NRANGE);
    int base4 = chunk * (BCH / 4);          // in int4 units
    int lim4 = E / 4;
#pragma unroll
    for (int rr = 0; rr < 2; ++rr) {
        int t4 = base4 + rr * 256 + threadIdx.x;
        if (t4 >= lim4) break;
        int4 p = pos4[t4];
        int e = t4 * 4;
        if (p.x >= lo && p.x < hi) idx[p.x] = e;
        if (p.y >= lo && p.y < hi) idx[p.y] = e + 1;
        if (p.z >= lo && p.z < hi) idx[p.z] = e + 2;
        if (p.w >= lo && p.w < hi) idx[p.w] = e + 3;
    }
}

// Check-node update. 128-thread blocks, 1 check/thread -> 2048 blocks
// -> 16 blocks/CU -> 32 waves/CU for latency hiding.
// first=1: gather llr[e/3] (v2c_0 == llr[var]); else gather v2c_e[e].
__global__ __launch_bounds__(128, 8) void check_kernel(
        const float* __restrict__ src,      // llr (first) or v2c_e
        const int* __restrict__ idx,
        float* __restrict__ c2v_s,
        const float* __restrict__ beta,
        const float* __restrict__ alpha,
        int t, int n_chk, int first) {
    int c = blockIdx.x * 128 + threadIdx.x;
    if (c >= n_chk) return;
    int base = c * DC_C;
    int2 i01 = *(const int2*)(idx + base);
    int2 i23 = *(const int2*)(idx + base + 2);
    int2 i45 = *(const int2*)(idx + base + 4);
    int e[DC_C] = {i01.x, i01.y, i23.x, i23.y, i45.x, i45.y};
    float v[DC_C];
    if (first) {
#pragma unroll
        for (int j = 0; j < DC_C; ++j) v[j] = src[e[j] / 3];
    } else {
#pragma unroll
        for (int j = 0; j < DC_C; ++j) v[j] = src[e[j]];
    }
    float b = beta[t];
    float a = alpha[t];
    float sg[DC_C], mg[DC_C];
    float sprod = 1.0f;
    float m1 = INFINITY, m2 = INFINITY;
#pragma unroll
    for (int j = 0; j < DC_C; ++j) {
        float x = v[j];
        float s = (x > 0.0f) ? 1.0f : ((x < 0.0f) ? -1.0f : 0.0f); // sign(0)=0
        float m = fabsf(x);
        sg[j] = s;
        mg[j] = m;
        sprod *= s;
        if (m < m1) { m2 = m1; m1 = m; }
        else if (m < m2) { m2 = m; }
    }
    float o[DC_C];
#pragma unroll
    for (int j = 0; j < DC_C; ++j) {
        // ties: mg[j]==m1 for multiple j implies m2==m1 -> identical to
        // the reference's first-argmin rule.
        float raw = (mg[j] == m1) ? m2 : m1;
        float val = fmaxf(raw - b, 0.0f) - a;
        o[j] = sprod * sg[j] * val;
    }
    *(float2*)(c2v_s + base)     = make_float2(o[0], o[1]);
    *(float2*)(c2v_s + base + 2) = make_float2(o[2], o[3]);
    *(float2*)(c2v_s + base + 4) = make_float2(o[4], o[5]);
}

// Variable-node update. 128-thread blocks, 1 var/thread -> 4096 blocks
// -> 32 waves/CU.
__global__ __launch_bounds__(128, 8) void var_kernel(
        const float* __restrict__ c2v_s,
        const int* __restrict__ pos,
        const float* __restrict__ llr,
        float* __restrict__ v2c_e,
        int n) {
    int v = blockIdx.x * 128 + threadIdx.x;
    if (v >= n) return;
    int p0 = pos[v * 3 + 0];
    int p1 = pos[v * 3 + 1];
    int p2 = pos[v * 3 + 2];
    float c0 = c2v_s[p0];
    float c1 = c2v_s[p1];
    float c2 = c2v_s[p2];
    float tot = (c0 + c1) + c2;
    float t = llr[v] + tot;
    v2c_e[v * 3 + 0] = t - c0;
    v2c_e[v * 3 + 1] = t - c1;
    v2c_e[v * 3 + 2] = t - c2;
}

// Final: posterior + hard decision. out[0..n)=bits(f32 0/1), out[n..2n)=post.
__global__ __launch_bounds__(128, 8) void final_kernel(
        const float* __restrict__ c2v_s,
        const int* __restrict__ pos,
        const float* __restrict__ llr,
        float* __restrict__ out,
        int n) {
    int v = blockIdx.x * 128 + threadIdx.x;
    if (v >= n) return;
    int p0 = pos[v * 3 + 0];
    int p1 = pos[v * 3 + 1];
    int p2 = pos[v * 3 + 2];
    float c0 = c2v_s[p0];
    float c1 = c2v_s[p1];
    float c2 = c2v_s[p2];
    float post = llr[v] + ((c0 + c1) + c2);
    out[v] = (post < 0.0f) ? 1.0f : 0.0f;
    out[n + v] = post;
}

extern "C" void kernel_launch(void* const* d_in, const int* in_sizes, int n_in,
                              void* d_out, int out_size, void* d_ws, size_t ws_size,
                              hipStream_t stream) {
    const float* llr      = (const float*)d_in[0];
    const float* beta     = (const float*)d_in[1];
    const float* alpha    = (const float*)d_in[2];
    const int*   edge_chk = (const int*)d_in[4];

    const int n  = in_sizes[0];       // 524288
    const int T  = in_sizes[1];       // 10
    const int E  = in_sizes[3];       // 1572864
    const int n_chk = E / DC_C;       // 262144

    // Workspace (rebuilt every call; ws re-poisoned between calls)
    char* ws = (char*)d_ws;
    int*   cnt   = (int*)ws;                              // n_chk ints (1 MB)
    int*   pos   = (int*)(ws + (size_t)n_chk * 4);        // E ints  (6 MB)
    int*   idx   = pos + E;                               // E ints  (6 MB)
    float* v2c_e = (float*)(idx + E);                     // E f32   (6 MB)
    float* c2v_s = v2c_e + E;                             // E f32   (6 MB)

    hipMemsetAsync(cnt, 0, (size_t)n_chk * 4, stream);
    {
        int E4 = E / 4;
        build_a<<<(E4 + 255) / 256, 256, 0, stream>>>((const int4*)edge_chk,
                                                      cnt, (int4*)pos, E4);
    }
    {
        int chunks = (E + BCH - 1) / BCH;
        build_b<<<chunks * NRANGE, 256, 0, stream>>>((const int4*)pos, idx, E);
    }
    for (int t = 0; t < T; ++t) {
        const float* src = (t == 0) ? llr : v2c_e;
        check_kernel<<<(n_chk + 127) / 128, 128, 0, stream>>>(
            src, idx, c2v_s, beta, alpha, t, n_chk, (t == 0) ? 1 : 0);
        if (t + 1 < T) {
            var_kernel<<<(n + 127) / 128, 128, 0, stream>>>(c2v_s, pos, llr,
                                                            v2c_e, n);
        } else {
            final_kernel<<<(n + 127) / 128, 128, 0, stream>>>(c2v_s, pos, llr,
                                                              (float*)d_out, n);
        }
    }
}

// Round 4
// 411.530 us; speedup vs baseline: 1.0959x; 1.0959x over previous
//
#include <hip/hip_runtime.h>
#include <math.h>

#define DC_C 6
#define NRANGE 8          // slot ranges, aligned to blockIdx%8 -> XCD round-robin
#define BCH 2048          // edges per block-chunk in build_b

// Phase A: per edge e, claim slot j in check c via device atomic, write
// pos[e] = c*6+j (coalesced int4). ~25G atomics/s is the fabric floor here.
__global__ void build_a(const int4* __restrict__ edge_chk4,
                        int* __restrict__ cnt,
                        int4* __restrict__ pos4,
                        int E4) {
    int t = blockIdx.x * blockDim.x + threadIdx.x;
    if (t >= E4) return;
    int4 c = edge_chk4[t];
    int j0 = atomicAdd(&cnt[c.x], 1);
    int j1 = atomicAdd(&cnt[c.y], 1);
    int j2 = atomicAdd(&cnt[c.z], 1);
    int j3 = atomicAdd(&cnt[c.w], 1);
    pos4[t] = make_int4(c.x * DC_C + j0, c.y * DC_C + j1,
                        c.z * DC_C + j2, c.w * DC_C + j3);
}

// Phase B: invert pos -> vmap (slot -> variable index = e/3). Only random
// write in the pipeline; range-partitioned so each vmap line is filled from
// one XCD (blockIdx%8 heuristic; perf-only, correctness-independent).
__global__ void build_b(const int4* __restrict__ pos4,
                        int* __restrict__ vmap,
                        int E) {
    int r = blockIdx.x & (NRANGE - 1);
    int chunk = blockIdx.x >> 3;
    int lo = r * (E / NRANGE);
    int hi = lo + (E / NRANGE);
    int base4 = chunk * (BCH / 4);          // in int4 units
    int lim4 = E / 4;
#pragma unroll
    for (int rr = 0; rr < 2; ++rr) {
        int t4 = base4 + rr * 256 + threadIdx.x;
        if (t4 >= lim4) break;
        int4 p = pos4[t4];
        int e = t4 * 4;
        if (p.x >= lo && p.x < hi) vmap[p.x] = e / 3;
        if (p.y >= lo && p.y < hi) vmap[p.y] = (e + 1) / 3;
        if (p.z >= lo && p.z < hi) vmap[p.z] = (e + 2) / 3;
        if (p.w >= lo && p.w < hi) vmap[p.w] = (e + 3) / 3;
    }
}

// Check-node update, posterior form. Thread c:
//   coalesced: vmap[6c..6c+5], OLD c2v_s[6c..6c+5] (own slots), NEW c2v write
//   random:    p[var_j] gathers from a 2MB array (fits per-XCD L2)
// v2c_j = p[var_j] - c2v_old_j  (== reference's (llr+tot)-c2v association;
// at t=0 c2v_old==0 and p==llr, so v2c==llr[var] bit-exact).
__global__ void check_kernel(const float* __restrict__ p,     // llr at t=0
                             const int* __restrict__ vmap,
                             float* __restrict__ c2v_s,
                             const float* __restrict__ beta,
                             const float* __restrict__ alpha,
                             int t, int n_chk) {
    int c = blockIdx.x * blockDim.x + threadIdx.x;
    if (c >= n_chk) return;
    int base = c * DC_C;
    int2 w01 = *(const int2*)(vmap + base);
    int2 w23 = *(const int2*)(vmap + base + 2);
    int2 w45 = *(const int2*)(vmap + base + 4);
    float2 o01 = *(const float2*)(c2v_s + base);
    float2 o23 = *(const float2*)(c2v_s + base + 2);
    float2 o45 = *(const float2*)(c2v_s + base + 4);
    int   w[DC_C]   = {w01.x, w01.y, w23.x, w23.y, w45.x, w45.y};
    float old_[DC_C] = {o01.x, o01.y, o23.x, o23.y, o45.x, o45.y};
    float pv[DC_C];
#pragma unroll
    for (int j = 0; j < DC_C; ++j) pv[j] = p[w[j]];
    float b = beta[t];
    float a = alpha[t];
    float sg[DC_C], mg[DC_C];
    float sprod = 1.0f;
    float m1 = INFINITY, m2 = INFINITY;
#pragma unroll
    for (int j = 0; j < DC_C; ++j) {
        float x = pv[j] - old_[j];
        float s = (x > 0.0f) ? 1.0f : ((x < 0.0f) ? -1.0f : 0.0f); // sign(0)=0
        float m = fabsf(x);
        sg[j] = s;
        mg[j] = m;
        sprod *= s;
        if (m < m1) { m2 = m1; m1 = m; }
        else if (m < m2) { m2 = m; }
    }
    float o[DC_C];
#pragma unroll
    for (int j = 0; j < DC_C; ++j) {
        // ties: mg[j]==m1 for multiple j implies m2==m1 -> identical to the
        // reference's first-argmin rule.
        float raw = (mg[j] == m1) ? m2 : m1;
        float val = fmaxf(raw - b, 0.0f) - a;
        o[j] = sprod * sg[j] * val;
    }
    *(float2*)(c2v_s + base)     = make_float2(o[0], o[1]);
    *(float2*)(c2v_s + base + 2) = make_float2(o[2], o[3]);
    *(float2*)(c2v_s + base + 4) = make_float2(o[4], o[5]);
}

// Variable-node update, posterior form. Thread v: coalesced pos[3v..3v+2] +
// llr[v], random gather of c2v_s (6MB footprint), coalesced write p[v].
__global__ void var_kernel(const float* __restrict__ c2v_s,
                           const int* __restrict__ pos,
                           const float* __restrict__ llr,
                           float* __restrict__ p,
                           int n) {
    int v = blockIdx.x * blockDim.x + threadIdx.x;
    if (v >= n) return;
    int p0 = pos[v * 3 + 0];
    int p1 = pos[v * 3 + 1];
    int p2 = pos[v * 3 + 2];
    float c0 = c2v_s[p0];
    float c1 = c2v_s[p1];
    float c2 = c2v_s[p2];
    p[v] = llr[v] + ((c0 + c1) + c2);
}

// Final: posterior + hard decision. out[0..n)=bits(f32 0/1), out[n..2n)=post.
__global__ void final_kernel(const float* __restrict__ c2v_s,
                             const int* __restrict__ pos,
                             const float* __restrict__ llr,
                             float* __restrict__ out,
                             int n) {
    int v = blockIdx.x * blockDim.x + threadIdx.x;
    if (v >= n) return;
    int p0 = pos[v * 3 + 0];
    int p1 = pos[v * 3 + 1];
    int p2 = pos[v * 3 + 2];
    float c0 = c2v_s[p0];
    float c1 = c2v_s[p1];
    float c2 = c2v_s[p2];
    float post = llr[v] + ((c0 + c1) + c2);
    out[v] = (post < 0.0f) ? 1.0f : 0.0f;
    out[n + v] = post;
}

extern "C" void kernel_launch(void* const* d_in, const int* in_sizes, int n_in,
                              void* d_out, int out_size, void* d_ws, size_t ws_size,
                              hipStream_t stream) {
    const float* llr      = (const float*)d_in[0];
    const float* beta     = (const float*)d_in[1];
    const float* alpha    = (const float*)d_in[2];
    const int*   edge_chk = (const int*)d_in[4];

    const int n  = in_sizes[0];       // 524288
    const int T  = in_sizes[1];       // 10
    const int E  = in_sizes[3];       // 1572864
    const int n_chk = E / DC_C;       // 262144

    // Workspace (rebuilt every call; ws re-poisoned between calls)
    char* ws = (char*)d_ws;
    int*   cnt   = (int*)ws;                              // n_chk ints (1 MB)
    int*   pos   = (int*)(ws + (size_t)n_chk * 4);        // E ints  (6 MB)
    int*   vmap  = pos + E;                               // E ints  (6 MB)
    float* c2v_s = (float*)(vmap + E);                    // E f32   (6 MB)
    float* p     = c2v_s + E;                             // n f32   (2 MB)

    hipMemsetAsync(cnt, 0, (size_t)n_chk * 4, stream);
    hipMemsetAsync(c2v_s, 0, (size_t)E * 4, stream);      // c2v_0 = 0
    {
        int E4 = E / 4;
        build_a<<<(E4 + 255) / 256, 256, 0, stream>>>((const int4*)edge_chk,
                                                      cnt, (int4*)pos, E4);
    }
    {
        int chunks = (E + BCH - 1) / BCH;
        build_b<<<chunks * NRANGE, 256, 0, stream>>>((const int4*)pos, vmap, E);
    }
    for (int t = 0; t < T; ++t) {
        const float* src = (t == 0) ? llr : p;   // p_init == llr, c2v_0 == 0
        check_kernel<<<(n_chk + 255) / 256, 256, 0, stream>>>(
            src, vmap, c2v_s, beta, alpha, t, n_chk);
        if (t + 1 < T) {
            var_kernel<<<(n + 255) / 256, 256, 0, stream>>>(c2v_s, pos, llr, p, n);
        } else {
            final_kernel<<<(n + 255) / 256, 256, 0, stream>>>(c2v_s, pos, llr,
                                                              (float*)d_out, n);
        }
    }
}

// Round 5
// 373.737 us; speedup vs baseline: 1.2067x; 1.1011x over previous
//
#include <hip/hip_runtime.h>
#include <math.h>

#define DC_C 6
#define NRANGE 8          // slot ranges, aligned to blockIdx%8 -> XCD round-robin
#define VCH 2048          // vars per block-chunk in build_b

// Per-check compressed message record (16 B, float4-gatherable).
// Asp = sprod * (relu(min2-b)-a)   [value for argmin edges]
// Bsp = sprod * (relu(min1-b)-a)   [value for all other edges]
// masks: bits 0-5 amin, bits 8-13 negative-sign, bits 16-21 zero-sign.
// c2v_j = sg_j * (amin_j ? Asp : Bsp), sg_j in {+1,-1,0}.

// Phase A: one thread per variable v; claims slots for its 3 edges
// (3v,3v+1,3v+2) via device atomics; writes packed pos64[v] (3x21 bits).
__global__ void build_a(const int* __restrict__ edge_chk,
                        int* __restrict__ cnt,
                        unsigned long long* __restrict__ pos64,
                        int n) {
    int v = blockIdx.x * blockDim.x + threadIdx.x;
    if (v >= n) return;
    int c0 = edge_chk[v * 3 + 0];
    int c1 = edge_chk[v * 3 + 1];
    int c2 = edge_chk[v * 3 + 2];
    int j0 = atomicAdd(&cnt[c0], 1);
    int j1 = atomicAdd(&cnt[c1], 1);
    int j2 = atomicAdd(&cnt[c2], 1);
    unsigned long long s0 = (unsigned long long)(c0 * DC_C + j0);
    unsigned long long s1 = (unsigned long long)(c1 * DC_C + j1);
    unsigned long long s2 = (unsigned long long)(c2 * DC_C + j2);
    pos64[v] = s0 | (s1 << 21) | (s2 << 42);
}

// Phase B: invert pos64 -> vmap (slot -> variable). Only random write in the
// pipeline; range-partitioned so each vmap line is filled from one XCD
// (blockIdx%8 heuristic; perf-only, correctness-independent).
__global__ void build_b(const unsigned long long* __restrict__ pos64,
                        int* __restrict__ vmap,
                        int n, int E) {
    int r = blockIdx.x & (NRANGE - 1);
    int chunk = blockIdx.x >> 3;
    int lo = r * (E / NRANGE);
    int hi = lo + (E / NRANGE);
    int base = chunk * VCH;
#pragma unroll
    for (int rr = 0; rr < VCH / 256; ++rr) {
        int v = base + rr * 256 + threadIdx.x;
        if (v >= n) break;
        unsigned long long pk = pos64[v];
        int s0 = (int)(pk & 0x1FFFFF);
        int s1 = (int)((pk >> 21) & 0x1FFFFF);
        int s2 = (int)((pk >> 42) & 0x1FFFFF);
        if (s0 >= lo && s0 < hi) vmap[s0] = v;
        if (s1 >= lo && s1 < hi) vmap[s1] = v;
        if (s2 >= lo && s2 < hi) vmap[s2] = v;
    }
}

// Check-node update. Thread c:
//   coalesced: vmap[6c..6c+5] (3x int2), own old record (float4), new record
//   random:    p[var_j] gathers from 2 MB (per-XCD L2-resident)
// v2c_j = p[w_j] - c2v_old_j; at t=0 (first=1): p==llr, c2v_old==0.
__global__ void check_kernel(const float* __restrict__ p,     // llr at t=0
                             const int* __restrict__ vmap,
                             float4* __restrict__ recs,
                             const float* __restrict__ beta,
                             const float* __restrict__ alpha,
                             int t, int n_chk, int first) {
    int c = blockIdx.x * blockDim.x + threadIdx.x;
    if (c >= n_chk) return;
    int base = c * DC_C;
    int2 w01 = *(const int2*)(vmap + base);
    int2 w23 = *(const int2*)(vmap + base + 2);
    int2 w45 = *(const int2*)(vmap + base + 4);
    int w[DC_C] = {w01.x, w01.y, w23.x, w23.y, w45.x, w45.y};
    float pv[DC_C];
#pragma unroll
    for (int j = 0; j < DC_C; ++j) pv[j] = p[w[j]];

    float old_[DC_C];
    if (first) {
#pragma unroll
        for (int j = 0; j < DC_C; ++j) old_[j] = 0.0f;
    } else {
        float4 rec = recs[c];
        unsigned int mk = __float_as_uint(rec.z);
        unsigned int am = mk & 0x3F;
        unsigned int ng = (mk >> 8) & 0x3F;
        unsigned int zr = (mk >> 16) & 0x3F;
#pragma unroll
        for (int j = 0; j < DC_C; ++j) {
            float val = ((am >> j) & 1) ? rec.x : rec.y;
            float s = ((zr >> j) & 1) ? 0.0f : (((ng >> j) & 1) ? -1.0f : 1.0f);
            old_[j] = s * val;
        }
    }

    float b = beta[t];
    float a = alpha[t];
    float sprod = 1.0f;
    float m1 = INFINITY, m2 = INFINITY;
    float mg[DC_C];
    unsigned int ng = 0, zr = 0;
#pragma unroll
    for (int j = 0; j < DC_C; ++j) {
        float x = pv[j] - old_[j];
        float m = fabsf(x);
        mg[j] = m;
        if (x < 0.0f) { ng |= (1u << j); sprod = -sprod; }
        else if (x == 0.0f) { zr |= (1u << j); sprod = 0.0f; }
        if (m < m1) { m2 = m1; m1 = m; }
        else if (m < m2) { m2 = m; }
    }
    unsigned int am = 0;
#pragma unroll
    for (int j = 0; j < DC_C; ++j) am |= (mg[j] == m1) ? (1u << j) : 0u;
    // ties: multiple amin bits imply m2==m1 -> A==B, identical to the
    // reference's first-argmin rule.
    float A = fmaxf(m2 - b, 0.0f) - a;
    float B = fmaxf(m1 - b, 0.0f) - a;
    float4 out;
    out.x = sprod * A;
    out.y = sprod * B;
    out.z = __uint_as_float(am | (ng << 8) | (zr << 16));
    out.w = 0.0f;
    recs[c] = out;
}

// Variable-node update. Thread v: coalesced pos64[v] + llr[v], 3 float4
// record gathers from a 4 MB L2-resident array, coalesced write p[v].
__device__ __forceinline__ float c2v_from_rec(float4 rec, int j) {
    unsigned int mk = __float_as_uint(rec.z);
    float val = ((mk >> j) & 1) ? rec.x : rec.y;
    float s = ((mk >> (16 + j)) & 1) ? 0.0f
            : (((mk >> (8 + j)) & 1) ? -1.0f : 1.0f);
    return s * val;
}

__global__ void var_kernel(const float4* __restrict__ recs,
                           const unsigned long long* __restrict__ pos64,
                           const float* __restrict__ llr,
                           float* __restrict__ p,
                           int n) {
    int v = blockIdx.x * blockDim.x + threadIdx.x;
    if (v >= n) return;
    unsigned long long pk = pos64[v];
    int s0 = (int)(pk & 0x1FFFFF);
    int s1 = (int)((pk >> 21) & 0x1FFFFF);
    int s2 = (int)((pk >> 42) & 0x1FFFFF);
    float4 r0 = recs[s0 / DC_C];
    float4 r1 = recs[s1 / DC_C];
    float4 r2 = recs[s2 / DC_C];
    float c0 = c2v_from_rec(r0, s0 % DC_C);
    float c1 = c2v_from_rec(r1, s1 % DC_C);
    float c2 = c2v_from_rec(r2, s2 % DC_C);
    p[v] = llr[v] + ((c0 + c1) + c2);
}

// Final: posterior + hard decision. out[0..n)=bits(f32 0/1), out[n..2n)=post.
__global__ void final_kernel(const float4* __restrict__ recs,
                             const unsigned long long* __restrict__ pos64,
                             const float* __restrict__ llr,
                             float* __restrict__ out,
                             int n) {
    int v = blockIdx.x * blockDim.x + threadIdx.x;
    if (v >= n) return;
    unsigned long long pk = pos64[v];
    int s0 = (int)(pk & 0x1FFFFF);
    int s1 = (int)((pk >> 21) & 0x1FFFFF);
    int s2 = (int)((pk >> 42) & 0x1FFFFF);
    float4 r0 = recs[s0 / DC_C];
    float4 r1 = recs[s1 / DC_C];
    float4 r2 = recs[s2 / DC_C];
    float c0 = c2v_from_rec(r0, s0 % DC_C);
    float c1 = c2v_from_rec(r1, s1 % DC_C);
    float c2 = c2v_from_rec(r2, s2 % DC_C);
    float post = llr[v] + ((c0 + c1) + c2);
    out[v] = (post < 0.0f) ? 1.0f : 0.0f;
    out[n + v] = post;
}

extern "C" void kernel_launch(void* const* d_in, const int* in_sizes, int n_in,
                              void* d_out, int out_size, void* d_ws, size_t ws_size,
                              hipStream_t stream) {
    const float* llr      = (const float*)d_in[0];
    const float* beta     = (const float*)d_in[1];
    const float* alpha    = (const float*)d_in[2];
    const int*   edge_chk = (const int*)d_in[4];

    const int n  = in_sizes[0];       // 524288
    const int T  = in_sizes[1];       // 10
    const int E  = in_sizes[3];       // 1572864
    const int n_chk = E / DC_C;       // 262144

    // Workspace (rebuilt every call; ws re-poisoned between calls)
    char* ws = (char*)d_ws;
    int*                 cnt   = (int*)ws;                       // 1 MB @ 0
    unsigned long long*  pos64 = (unsigned long long*)(ws + (1u << 20));   // 4 MB @ 1 MB
    int*                 vmap  = (int*)(ws + (5u << 20));        // 6 MB @ 5 MB
    float4*              recs  = (float4*)(ws + (11u << 20));    // 4 MB @ 11 MB
    float*               p     = (float*)(ws + (15u << 20));     // 2 MB @ 15 MB

    hipMemsetAsync(cnt, 0, (size_t)n_chk * 4, stream);
    build_a<<<(n + 255) / 256, 256, 0, stream>>>(edge_chk, cnt, pos64, n);
    {
        int chunks = (n + VCH - 1) / VCH;
        build_b<<<chunks * NRANGE, 256, 0, stream>>>(pos64, vmap, n, E);
    }
    for (int t = 0; t < T; ++t) {
        const float* src = (t == 0) ? llr : p;   // p_init == llr, c2v_0 == 0
        check_kernel<<<(n_chk + 255) / 256, 256, 0, stream>>>(
            src, vmap, recs, beta, alpha, t, n_chk, (t == 0) ? 1 : 0);
        if (t + 1 < T) {
            var_kernel<<<(n + 255) / 256, 256, 0, stream>>>(recs, pos64, llr, p, n);
        } else {
            final_kernel<<<(n + 255) / 256, 256, 0, stream>>>(recs, pos64, llr,
                                                              (float*)d_out, n);
        }
    }
}